// Round 6
// baseline (4162.233 us; speedup 1.0000x reference)
//
#include <hip/hip_runtime.h>

// ---------------------------------------------------------------------------
// VoxelSetAbstraction forward (PV-RCNN style) for MI355X
//   B=2, N_RAW=16384, N_KP=2048, M_VOX=8192, C_VOX=64
//   BEV: (2,256,200,176), stride 8, voxel 0.05, pc_min (0,-40,-3)
//   raw SA: radii (0.4,0.8) ns (16,16), MLP 4->16->16
//   conv SA: radii (1.2,2.4) ns (16,32), MLP 67->64->64
//   fusion: 416 -> 128
// ---------------------------------------------------------------------------

#define NRAW   16384
#define MVOX   8192
#define NKP    2048
#define NKPALL 4096   // B * NKP

__device__ __constant__ float kBNS = (float)0.9999950000374997; // 1/sqrt(1+1e-5)

// ---------------------------------------------------------------------------
// K0: pack points to interleaved float4 (x,y,z,intensity) + voxel centers
// ---------------------------------------------------------------------------
__global__ __launch_bounds__(256) void prep_kernel(
    const float* __restrict__ pts, const int* __restrict__ vc,
    float4* __restrict__ xyz4, float4* __restrict__ cxyz4) {
#pragma clang fp contract(off)
  int i = blockIdx.x * 256 + threadIdx.x;
  if (i < 2 * NRAW) {
    const float* p = pts + (size_t)i * 5;
    xyz4[i] = make_float4(p[1], p[2], p[3], p[4]);
  }
  if (i < 2 * MVOX) {
    const int* v = vc + (size_t)i * 4;
    cxyz4[i] = make_float4(((float)v[3] + 0.5f) * 0.2f + 0.0f,
                           ((float)v[2] + 0.5f) * 0.2f + -40.0f,
                           ((float)v[1] + 0.5f) * 0.4f + -3.0f, 0.f);
  }
}

// ---------------------------------------------------------------------------
// Wave-wide u32 max via DPP (VALU pipe, zero DS). Lane 63 holds the result.
// 4 in-row stages (quad xor1, xor2, ror4, ror8) give every lane its row max;
// row_bcast15/31 funnel to lanes 48-63. Values must be >= 0 as u32.
// ---------------------------------------------------------------------------
__device__ __forceinline__ unsigned wave_umax63(unsigned v) {
  unsigned t;
  t = (unsigned)__builtin_amdgcn_update_dpp(0, (int)v, 0xB1,  0xf, 0xf, true); v = v < t ? t : v;
  t = (unsigned)__builtin_amdgcn_update_dpp(0, (int)v, 0x4E,  0xf, 0xf, true); v = v < t ? t : v;
  t = (unsigned)__builtin_amdgcn_update_dpp(0, (int)v, 0x124, 0xf, 0xf, true); v = v < t ? t : v;
  t = (unsigned)__builtin_amdgcn_update_dpp(0, (int)v, 0x128, 0xf, 0xf, true); v = v < t ? t : v;
  t = (unsigned)__builtin_amdgcn_update_dpp(0, (int)v, 0x142, 0xa, 0xf, true); v = v < t ? t : v;
  t = (unsigned)__builtin_amdgcn_update_dpp(0, (int)v, 0x143, 0xc, 0xf, true); v = v < t ? t : v;
  return v;  // valid in lane 63
}

// ---------------------------------------------------------------------------
// K1: farthest point sampling. One block/batch, 512 thr, 32 pts/thread in
// ARCH VGPRs (launch_bounds(512,1): 512-reg budget -> no AGPR shuffling,
// which cost ~400 cyc/SIMD/iter in rounds 4-5 at VGPR_Count=84).
// Scalar f32 only: v_pk_*_f32 occupies the SIMD twice as long (round-5 PMC:
// VALUBusy flat) -- packed f32 is NOT a throughput win on CDNA4.
// Per iteration, ONE barrier:
//   dist update (exact numpy order) -> fmax tree -> vb
//   DPP wave val-max (lane63) -> readlane -> wmax
//   tied lanes scan regs descending (y-half then x-half) -> first global idx
//   DPP wave umax of ~idx -> lane63 ds_max_u64 of (wmax<<32 | ~idx)
//   barrier; all read slot -> winner idx -> one s_load_dwordx4 of coords
// Slot triple-buffered (s%3, reset (s+2)%3): with one barrier/iter a wave
// may run one iteration ahead, so a 2-slot scheme would race the reset.
// ---------------------------------------------------------------------------
__global__ __launch_bounds__(512, 1) void fps_kernel(
    const float4* __restrict__ xyz4,
    float* __restrict__ kx, float* __restrict__ ky, float* __restrict__ kz) {
#pragma clang fp contract(off)
  const int b = blockIdx.x;
  const int t = threadIdx.x;
  const float4* bp = xyz4 + b * NRAW;

  // j < 16: point j*512+t (x-half); j >= 16: point 8192+(j-16)*512+t (y-half)
  float px[32], py[32], pz[32], dd[32];
#pragma unroll
  for (int j = 0; j < 16; ++j) {
    const float4 a = bp[j * 512 + t];
    const float4 c = bp[8192 + j * 512 + t];
    px[j] = a.x; py[j] = a.y; pz[j] = a.z; dd[j] = 1e10f;
    px[j + 16] = c.x; py[j + 16] = c.y; pz[j + 16] = c.z; dd[j + 16] = 1e10f;
  }

  const float4 p0 = bp[0];
  float lx = p0.x, ly = p0.y, lz = p0.z;
  if (t == 0) { kx[b * NKP] = lx; ky[b * NKP] = ly; kz[b * NKP] = lz; }

  __shared__ unsigned long long slot_m[3];
  if (t == 0) { slot_m[0] = 0ULL; slot_m[1] = 0ULL; slot_m[2] = 0ULL; }
  __syncthreads();

  for (int s = 1; s < NKP; ++s) {
    const int slot = s % 3;
#pragma unroll
    for (int j = 0; j < 32; ++j) {
      float dx = px[j] - lx, dy = py[j] - ly, dz = pz[j] - lz;
      float d2 = dx * dx; d2 = d2 + dy * dy; d2 = d2 + dz * dz;
      dd[j] = fminf(dd[j], d2);
    }
    // 31-op fmax tree (fmax of equal-value f32 bits is bit-stable)
    float m16[16];
#pragma unroll
    for (int j = 0; j < 16; ++j) m16[j] = fmaxf(dd[2 * j], dd[2 * j + 1]);
    float m8[8];
#pragma unroll
    for (int j = 0; j < 8; ++j) m8[j] = fmaxf(m16[2 * j], m16[2 * j + 1]);
    float m4[4];
#pragma unroll
    for (int j = 0; j < 4; ++j) m4[j] = fmaxf(m8[2 * j], m8[2 * j + 1]);
    const float bv = fmaxf(fmaxf(m4[0], m4[1]), fmaxf(m4[2], m4[3]));

    const unsigned vb = __float_as_uint(bv);
    const unsigned wmax =
        (unsigned)__builtin_amdgcn_readlane((int)wave_umax63(vb), 63);

    // first (smallest) matching global index in this lane; only lanes tied
    // with the wave max participate (others contribute identity 0)
    int bi = 0;
    if (vb == wmax) {
#pragma unroll
      for (int j = 31; j >= 16; --j)          // y-half: larger global indices
        if (__float_as_uint(dd[j]) == wmax) bi = 8192 + (j - 16) * 512 + t;
#pragma unroll
      for (int j = 15; j >= 0; --j)           // x-half wins over y-half
        if (__float_as_uint(dd[j]) == wmax) bi = j * 512 + t;
    }
    const unsigned cand = (vb == wmax) ? ~(unsigned)bi : 0u;
    const unsigned cm = wave_umax63(cand);    // lane63: wave min-idx (as ~idx)
    if ((t & 63) == 63)
      atomicMax(&slot_m[slot], ((unsigned long long)wmax << 32) |
                               (unsigned long long)cm);
    __syncthreads();

    const unsigned long long gpk = slot_m[slot];
    const int wi = __builtin_amdgcn_readfirstlane((int)~(unsigned)gpk);
    if (t == 0) slot_m[(s + 2) % 3] = 0ULL;   // used again at iter s+2
    const float4 cw = bp[wi];                 // uniform -> s_load_dwordx4
    lx = cw.x; ly = cw.y; lz = cw.z;
    if (t == 0) { kx[b * NKP + s] = lx; ky[b * NKP + s] = ly; kz[b * NKP + s] = lz; }
  }
}

// ---------------------------------------------------------------------------
// K2: BEV bilinear. one block per keypoint, 256 threads = 256 channels.
// ---------------------------------------------------------------------------
__global__ __launch_bounds__(256) void bev_kernel(
    const float* __restrict__ sf, const float* __restrict__ kx,
    const float* __restrict__ ky, float* __restrict__ feats) {
#pragma clang fp contract(off)
  const int kidx = blockIdx.x;
  const int c = threadIdx.x;
  const int b = kidx >> 11;
  const float x = (kx[kidx] - 0.0f) / 0.05f / 8.0f;
  const float y = (ky[kidx] - (-40.0f)) / 0.05f / 8.0f;
  const float xf = floorf(x), yf = floorf(y);
  int x0 = (int)xf;     x0 = x0 < 0 ? 0 : (x0 > 175 ? 175 : x0);
  int x1 = (int)xf + 1; x1 = x1 < 0 ? 0 : (x1 > 175 ? 175 : x1);
  int y0 = (int)yf;     y0 = y0 < 0 ? 0 : (y0 > 199 ? 199 : y0);
  int y1 = (int)yf + 1; y1 = y1 < 0 ? 0 : (y1 > 199 ? 199 : y1);
  const float x0f = (float)x0, x1f = (float)x1, y0f = (float)y0, y1f = (float)y1;
  const float wa = (x - x0f) * (y1f - y);
  const float wb = (x1f - x) * (y1f - y);
  const float wc = (x1f - x) * (y - y0f);
  const float wd = (x - x0f) * (y - y0f);
  const float* base = sf + ((size_t)b * 256 + c) * (200 * 176);
  const float fa = base[y1 * 176 + x0];
  const float fb = base[y1 * 176 + x1];
  const float fc = base[y0 * 176 + x1];
  const float fd = base[y0 * 176 + x0];
  float r = fd * wb; r = r + fc * wa; r = r + fa * wc; r = r + fb * wd;
  feats[(size_t)kidx * 416 + c] = r;
}

// ---------------------------------------------------------------------------
// K3: raw SA. one wave per (keypoint, radius). MLP 4->16->16, max-pool.
// ---------------------------------------------------------------------------
__global__ __launch_bounds__(256) void raw_sa_kernel(
    const float4* __restrict__ xyz4,
    const float* __restrict__ kx, const float* __restrict__ ky,
    const float* __restrict__ kz,
    const float* __restrict__ w0, const float* __restrict__ g0,
    const float* __restrict__ b0, const float* __restrict__ w1,
    const float* __restrict__ g1, const float* __restrict__ b1,
    float* __restrict__ feats) {
  const int wv = threadIdx.x >> 6;
  const int lane = threadIdx.x & 63;
  const int gw = blockIdx.x * 4 + wv;       // 0..8191
  const int ri = gw >> 12;                  // radius index 0/1
  const int kidx = gw & 4095;
  const int b = kidx >> 11;
  const float R2 = ri ? (float)(0.8 * 0.8) : (float)(0.4 * 0.4);

  __shared__ int   idxl[4][16];
  __shared__ float hbuf[4][16][17];

  const float kxv = kx[kidx], kyv = ky[kidx], kzv = kz[kidx];
  const int base = b * NRAW;
  int cnt = 0;
  {
#pragma clang fp contract(off)
    for (int ch = 0; ch < NRAW / 64 && cnt < 16; ++ch) {
      const float4 q = xyz4[base + ch * 64 + lane];
      float dx = kxv - q.x, dy = kyv - q.y, dz = kzv - q.z;
      float d2 = dx * dx; d2 = d2 + dy * dy; d2 = d2 + dz * dz;
      unsigned long long m = __ballot(d2 < R2);
      while (m && cnt < 16) {
        int bit = __builtin_ctzll(m);
        if (lane == 0) idxl[wv][cnt] = ch * 64 + bit;
        ++cnt;
        m &= m - 1;
      }
    }
  }
  const int outoff = kidx * 416 + 256 + ri * 16;
  if (cnt == 0) {
    if (lane < 16) feats[outoff + lane] = 0.f;
    return;
  }
  __threadfence_block();

  const int s = lane & 15, cq = lane >> 4;
  const int ss = (s < cnt) ? s : 0;          // duplicate sample 0 (matches ref pad)
  const float4 q = xyz4[base + idxl[wv][ss]];
  const float gx = q.x - kxv, gy = q.y - kyv, gz = q.z - kzv, gi = q.w;
  const int wb0 = ri * 64, cb = ri * 16;
#pragma unroll
  for (int j = 0; j < 4; ++j) {
    int c = cq * 4 + j;
    float a = gx * w0[wb0 + c];
    a = fmaf(gy, w0[wb0 + 16 + c], a);
    a = fmaf(gz, w0[wb0 + 32 + c], a);
    a = fmaf(gi, w0[wb0 + 48 + c], a);
    a = fmaf(a, g0[cb + c] * kBNS, b0[cb + c]);
    hbuf[wv][s][c] = fmaxf(a, 0.f);
  }
  __threadfence_block();
  float o0 = 0.f, o1 = 0.f, o2 = 0.f, o3 = 0.f;
  const int wb1 = ri * 256;
#pragma unroll
  for (int k = 0; k < 16; ++k) {
    float hk = hbuf[wv][s][k];
    o0 = fmaf(hk, w1[wb1 + k * 16 + cq * 4 + 0], o0);
    o1 = fmaf(hk, w1[wb1 + k * 16 + cq * 4 + 1], o1);
    o2 = fmaf(hk, w1[wb1 + k * 16 + cq * 4 + 2], o2);
    o3 = fmaf(hk, w1[wb1 + k * 16 + cq * 4 + 3], o3);
  }
  float v0 = fmaxf(fmaf(o0, g1[cb + cq * 4 + 0] * kBNS, b1[cb + cq * 4 + 0]), 0.f);
  float v1 = fmaxf(fmaf(o1, g1[cb + cq * 4 + 1] * kBNS, b1[cb + cq * 4 + 1]), 0.f);
  float v2 = fmaxf(fmaf(o2, g1[cb + cq * 4 + 2] * kBNS, b1[cb + cq * 4 + 2]), 0.f);
  float v3 = fmaxf(fmaf(o3, g1[cb + cq * 4 + 3] * kBNS, b1[cb + cq * 4 + 3]), 0.f);
#pragma unroll
  for (int off = 1; off < 16; off <<= 1) {
    v0 = fmaxf(v0, __shfl_xor(v0, off, 64));
    v1 = fmaxf(v1, __shfl_xor(v1, off, 64));
    v2 = fmaxf(v2, __shfl_xor(v2, off, 64));
    v3 = fmaxf(v3, __shfl_xor(v3, off, 64));
  }
  if (s == 0) {
    feats[outoff + cq * 4 + 0] = v0;
    feats[outoff + cq * 4 + 1] = v1;
    feats[outoff + cq * 4 + 2] = v2;
    feats[outoff + cq * 4 + 3] = v3;
  }
}

// ---------------------------------------------------------------------------
// K4: conv SA. one wave per (keypoint, radius). MLP 67->64->64, max-pool.
// ---------------------------------------------------------------------------
__global__ __launch_bounds__(256) void conv_sa_kernel(
    const float4* __restrict__ cxyz4, const float* __restrict__ vf,
    const float* __restrict__ kx, const float* __restrict__ ky,
    const float* __restrict__ kz,
    const float* __restrict__ w0, const float* __restrict__ g0,
    const float* __restrict__ b0, const float* __restrict__ w1,
    const float* __restrict__ g1, const float* __restrict__ b1,
    float* __restrict__ feats) {
  const int wv = threadIdx.x >> 6;
  const int lane = threadIdx.x & 63;
  const int gw = blockIdx.x * 4 + wv;
  const int ri = gw >> 12;
  const int kidx = gw & 4095;
  const int b = kidx >> 11;
  const int NS = ri ? 32 : 16;
  const float R2 = ri ? (float)(2.4 * 2.4) : (float)(1.2 * 1.2);

  __shared__ int   idxl[4][32];
  __shared__ float gbuf[4][64];
  __shared__ float hbuf[4][32][64];

  const float kxv = kx[kidx], kyv = ky[kidx], kzv = kz[kidx];
  const int base = b * MVOX;
  int cnt = 0;
  {
#pragma clang fp contract(off)
    for (int ch = 0; ch < MVOX / 64 && cnt < NS; ++ch) {
      const float4 q = cxyz4[base + ch * 64 + lane];
      float dx = kxv - q.x, dy = kyv - q.y, dz = kzv - q.z;
      float d2 = dx * dx; d2 = d2 + dy * dy; d2 = d2 + dz * dz;
      unsigned long long m = __ballot(d2 < R2);
      while (m && cnt < NS) {
        int bit = __builtin_ctzll(m);
        if (lane == 0) idxl[wv][cnt] = ch * 64 + bit;
        ++cnt;
        m &= m - 1;
      }
    }
  }
  const int outoff = kidx * 416 + 288 + ri * 64;
  if (cnt == 0) {
    feats[outoff + lane] = 0.f;
    return;
  }
  __threadfence_block();

  // per-lane weight columns (lane == output channel)
  const float wA0 = w0[(ri * 67 + 0) * 64 + lane];
  const float wA1 = w0[(ri * 67 + 1) * 64 + lane];
  const float wA2 = w0[(ri * 67 + 2) * 64 + lane];
  float wB[64];
#pragma unroll
  for (int k = 0; k < 64; ++k) wB[k] = w0[(ri * 67 + 3 + k) * 64 + lane];
  float wC[64];
#pragma unroll
  for (int k = 0; k < 64; ++k) wC[k] = w1[(ri * 64 + k) * 64 + lane];
  const float s0 = g0[ri * 64 + lane] * kBNS, bb0 = b0[ri * 64 + lane];
  const float s1 = g1[ri * 64 + lane] * kBNS, bb1 = b1[ri * 64 + lane];

  for (int sm = 0; sm < cnt; ++sm) {
    const int p = base + idxl[wv][sm];
    const float4 q = cxyz4[p];
    const float ox = q.x - kxv, oy = q.y - kyv, oz = q.z - kzv;
    gbuf[wv][lane] = vf[(size_t)p * 64 + lane];
    __threadfence_block();
    float acc = ox * wA0;
    acc = fmaf(oy, wA1, acc);
    acc = fmaf(oz, wA2, acc);
#pragma unroll
    for (int k4 = 0; k4 < 16; ++k4) {
      float4 g4 = *(const float4*)&gbuf[wv][k4 * 4];
      acc = fmaf(g4.x, wB[k4 * 4 + 0], acc);
      acc = fmaf(g4.y, wB[k4 * 4 + 1], acc);
      acc = fmaf(g4.z, wB[k4 * 4 + 2], acc);
      acc = fmaf(g4.w, wB[k4 * 4 + 3], acc);
    }
    hbuf[wv][sm][lane] = fmaxf(fmaf(acc, s0, bb0), 0.f);
    __threadfence_block();
  }
  float mx = -1e30f;
  for (int sm = 0; sm < cnt; ++sm) {
    float acc = 0.f;
#pragma unroll
    for (int k4 = 0; k4 < 16; ++k4) {
      float4 h4 = *(const float4*)&hbuf[wv][sm][k4 * 4];
      acc = fmaf(h4.x, wC[k4 * 4 + 0], acc);
      acc = fmaf(h4.y, wC[k4 * 4 + 1], acc);
      acc = fmaf(h4.z, wC[k4 * 4 + 2], acc);
      acc = fmaf(h4.w, wC[k4 * 4 + 3], acc);
    }
    mx = fmaxf(mx, fmaxf(fmaf(acc, s1, bb1), 0.f));
  }
  feats[outoff + lane] = mx;
}

// ---------------------------------------------------------------------------
// K5: fusion 416 -> 128 + BN + ReLU. one thread per (kp, out-channel).
// ---------------------------------------------------------------------------
__global__ __launch_bounds__(256) void fusion_kernel(
    const float* __restrict__ feats, const float* __restrict__ fw,
    const float* __restrict__ fg, const float* __restrict__ fb,
    float* __restrict__ out) {
  const int gid = blockIdx.x * 256 + threadIdx.x;
  const int kidx = gid >> 7, c = gid & 127;
  const float* f = feats + (size_t)kidx * 416;
  float acc = 0.f;
#pragma unroll 4
  for (int k = 0; k < 416; k += 4) {
    float4 fv = *(const float4*)(f + k);
    acc = fmaf(fv.x, fw[(k + 0) * 128 + c], acc);
    acc = fmaf(fv.y, fw[(k + 1) * 128 + c], acc);
    acc = fmaf(fv.z, fw[(k + 2) * 128 + c], acc);
    acc = fmaf(fv.w, fw[(k + 3) * 128 + c], acc);
  }
  out[gid] = fmaxf(fmaf(acc, fg[c] * kBNS, fb[c]), 0.f);
}

// ---------------------------------------------------------------------------
extern "C" void kernel_launch(void* const* d_in, const int* in_sizes, int n_in,
                              void* d_out, int out_size, void* d_ws, size_t ws_size,
                              hipStream_t stream) {
  (void)in_sizes; (void)n_in; (void)out_size; (void)ws_size;
  const float* pts = (const float*)d_in[0];
  const float* sf  = (const float*)d_in[1];
  const int*   vc  = (const int*)d_in[2];
  const float* vf  = (const float*)d_in[3];
  const float* raw_w0 = (const float*)d_in[4];
  const float* raw_g0 = (const float*)d_in[5];
  const float* raw_b0 = (const float*)d_in[6];
  const float* raw_w1 = (const float*)d_in[7];
  const float* raw_g1 = (const float*)d_in[8];
  const float* raw_b1 = (const float*)d_in[9];
  const float* conv_w0 = (const float*)d_in[10];
  const float* conv_g0 = (const float*)d_in[11];
  const float* conv_b0 = (const float*)d_in[12];
  const float* conv_w1 = (const float*)d_in[13];
  const float* conv_g1 = (const float*)d_in[14];
  const float* conv_b1 = (const float*)d_in[15];
  const float* fus_w = (const float*)d_in[16];
  const float* fus_g = (const float*)d_in[17];
  const float* fus_b = (const float*)d_in[18];
  float* out = (float*)d_out;

  float* W = (float*)d_ws;
  float4* xyz4  = (float4*)W;             // 32768 float4 = 131072 floats
  float4* cxyz4 = (float4*)(W + 131072);  // 16384 float4 = 65536 floats
  float* kx    = W + 196608;              // 4096 each
  float* ky    = W + 200704;
  float* kz    = W + 204800;
  float* feats = W + 208896;              // 4096 * 416

  prep_kernel<<<128, 256, 0, stream>>>(pts, vc, xyz4, cxyz4);
  fps_kernel<<<2, 512, 0, stream>>>(xyz4, kx, ky, kz);
  bev_kernel<<<NKPALL, 256, 0, stream>>>(sf, kx, ky, feats);
  raw_sa_kernel<<<2048, 256, 0, stream>>>(xyz4, kx, ky, kz,
                                          raw_w0, raw_g0, raw_b0, raw_w1, raw_g1, raw_b1,
                                          feats);
  conv_sa_kernel<<<2048, 256, 0, stream>>>(cxyz4, vf, kx, ky, kz,
                                           conv_w0, conv_g0, conv_b0, conv_w1, conv_g1, conv_b1,
                                           feats);
  fusion_kernel<<<2048, 256, 0, stream>>>(feats, fus_w, fus_g, fus_b, out);
}

// Round 7
// 2918.004 us; speedup vs baseline: 1.4264x; 1.4264x over previous
//
#include <hip/hip_runtime.h>

// ---------------------------------------------------------------------------
// VoxelSetAbstraction forward (PV-RCNN style) for MI355X
//   B=2, N_RAW=16384, N_KP=2048, M_VOX=8192, C_VOX=64
//   BEV: (2,256,200,176), stride 8, voxel 0.05, pc_min (0,-40,-3)
//   raw SA: radii (0.4,0.8) ns (16,16), MLP 4->16->16
//   conv SA: radii (1.2,2.4) ns (16,32), MLP 67->64->64
//   fusion: 416 -> 128
// ---------------------------------------------------------------------------

#define NRAW   16384
#define MVOX   8192
#define NKP    2048
#define NKPALL 4096   // B * NKP

__device__ __constant__ float kBNS = (float)0.9999950000374997; // 1/sqrt(1+1e-5)

// ---------------------------------------------------------------------------
// K0: pack points to interleaved float4 (x,y,z,intensity) + voxel centers
// ---------------------------------------------------------------------------
__global__ __launch_bounds__(256) void prep_kernel(
    const float* __restrict__ pts, const int* __restrict__ vc,
    float4* __restrict__ xyz4, float4* __restrict__ cxyz4) {
#pragma clang fp contract(off)
  int i = blockIdx.x * 256 + threadIdx.x;
  if (i < 2 * NRAW) {
    const float* p = pts + (size_t)i * 5;
    xyz4[i] = make_float4(p[1], p[2], p[3], p[4]);
  }
  if (i < 2 * MVOX) {
    const int* v = vc + (size_t)i * 4;
    cxyz4[i] = make_float4(((float)v[3] + 0.5f) * 0.2f + 0.0f,
                           ((float)v[2] + 0.5f) * 0.2f + -40.0f,
                           ((float)v[1] + 0.5f) * 0.4f + -3.0f, 0.f);
  }
}

// ---------------------------------------------------------------------------
// K0b: y-histogram sort (256 bins) per batch -> sx4 (sorted coords) + sperm
// (sorted-pos -> original local index). Gives each fps wave (1024 contiguous
// sorted points) a compact y-strip (~5m) for bbox pruning. Order inside a
// bin is nondeterministic (atomic ranks) but FPS output is order-invariant:
// per-point math is elementwise, max over a set is order-free, and ties are
// resolved by ORIGINAL index via sperm.
// ---------------------------------------------------------------------------
__global__ __launch_bounds__(1024) void sort_kernel(
    const float* __restrict__ pts, float4* __restrict__ sx4,
    int* __restrict__ sperm) {
  const int b = blockIdx.x, t = threadIdx.x;
  __shared__ unsigned hist[256], base[256], cur[256];
  if (t < 256) hist[t] = 0u;
  __syncthreads();
  int bins[16];
#pragma unroll
  for (int k = 0; k < 16; ++k) {
    const int i = k * 1024 + t;
    const float y = pts[(size_t)(b * NRAW + i) * 5 + 2];
    int bin = (int)((y + 40.0f) * 3.2f);
    bin = bin < 0 ? 0 : (bin > 255 ? 255 : bin);
    bins[k] = bin;
    atomicAdd(&hist[bin], 1u);
  }
  __syncthreads();
  if (t == 0) {
    unsigned acc = 0;
    for (int i = 0; i < 256; ++i) { base[i] = acc; cur[i] = acc; acc += hist[i]; }
  }
  __syncthreads();
#pragma unroll
  for (int k = 0; k < 16; ++k) {
    const int i = k * 1024 + t;
    const unsigned pos = atomicAdd(&cur[bins[k]], 1u);
    const float* p = pts + (size_t)(b * NRAW + i) * 5;
    sx4[b * NRAW + pos] = make_float4(p[1], p[2], p[3], 0.f);
    sperm[b * NRAW + pos] = i;
  }
}

// ---------------------------------------------------------------------------
// Wave-wide u32 max via DPP (VALU pipe, zero DS). Lane 63 holds the result.
// ---------------------------------------------------------------------------
__device__ __forceinline__ unsigned wave_umax63(unsigned v) {
  unsigned t;
  t = (unsigned)__builtin_amdgcn_update_dpp(0, (int)v, 0xB1,  0xf, 0xf, true); v = v < t ? t : v;
  t = (unsigned)__builtin_amdgcn_update_dpp(0, (int)v, 0x4E,  0xf, 0xf, true); v = v < t ? t : v;
  t = (unsigned)__builtin_amdgcn_update_dpp(0, (int)v, 0x124, 0xf, 0xf, true); v = v < t ? t : v;
  t = (unsigned)__builtin_amdgcn_update_dpp(0, (int)v, 0x128, 0xf, 0xf, true); v = v < t ? t : v;
  t = (unsigned)__builtin_amdgcn_update_dpp(0, (int)v, 0x142, 0xa, 0xf, true); v = v < t ? t : v;
  t = (unsigned)__builtin_amdgcn_update_dpp(0, (int)v, 0x143, 0xc, 0xf, true); v = v < t ? t : v;
  return v;  // valid in lane 63
}

// ---------------------------------------------------------------------------
// K1: farthest point sampling with EXACT bbox pruning.
// 1024 thr (16 waves), wave w owns sorted positions [w*1024, (w+1)*1024)
// (a compact y-strip), 16 pts/thread in registers.
// Per iteration:
//   skip test: LB2 = dist^2(center, wave bbox); if LB2*0.9999 > bv_wave
//     (conservative: f32 eval error ~4ulp << 1e-4) then NO dd can change and
//     the wave's cached packed candidate is still valid -> just re-post it.
//   active: dd=min(dd,d2) (exact numpy order), fmax tree -> bv, DPP wave max,
//     tied lanes look up ORIGINAL index in LDS perm, DPP min-idx, cache
//     (val<<32 | ~minidx).
//   all waves: lane63 ds atomicMax(slot[s%3], cached); ONE barrier; read slot;
//   winner coords via uniform s_load from ORIGINAL-order xyz4.
// Slot triple-buffered (reset (s+2)%3 post-barrier) as validated in r6.
// ---------------------------------------------------------------------------
__global__ __launch_bounds__(1024, 4) void fps_kernel(
    const float4* __restrict__ sx4, const int* __restrict__ sperm,
    const float4* __restrict__ xyz4,
    float* __restrict__ kx, float* __restrict__ ky, float* __restrict__ kz) {
#pragma clang fp contract(off)
  const int b = blockIdx.x;
  const int t = threadIdx.x;
  const int w = t >> 6, lane = t & 63;
  const int wb = w * 1024;
  const float4* sp = sx4 + b * NRAW;

  __shared__ int perm[NRAW];
  __shared__ unsigned long long slot[3];

  float px[16], py[16], pz[16], dd[16];
#pragma unroll
  for (int j = 0; j < 16; ++j) {
    const float4 q = sp[wb + j * 64 + lane];
    px[j] = q.x; py[j] = q.y; pz[j] = q.z; dd[j] = 1e10f;
  }
#pragma unroll
  for (int k = 0; k < 16; ++k)
    perm[k * 1024 + t] = sperm[b * NRAW + k * 1024 + t];
  if (t < 3) slot[t] = 0ULL;

  // wave bbox (one-time): per-lane min/max then 6-stage shuffle reduce
  float bnx = px[0], bxx = px[0], bny = py[0], bxy = py[0], bnz = pz[0], bxz = pz[0];
#pragma unroll
  for (int j = 1; j < 16; ++j) {
    bnx = fminf(bnx, px[j]); bxx = fmaxf(bxx, px[j]);
    bny = fminf(bny, py[j]); bxy = fmaxf(bxy, py[j]);
    bnz = fminf(bnz, pz[j]); bxz = fmaxf(bxz, pz[j]);
  }
#pragma unroll
  for (int off = 1; off < 64; off <<= 1) {
    bnx = fminf(bnx, __shfl_xor(bnx, off, 64));
    bxx = fmaxf(bxx, __shfl_xor(bxx, off, 64));
    bny = fminf(bny, __shfl_xor(bny, off, 64));
    bxy = fmaxf(bxy, __shfl_xor(bxy, off, 64));
    bnz = fminf(bnz, __shfl_xor(bnz, off, 64));
    bxz = fmaxf(bxz, __shfl_xor(bxz, off, 64));
  }

  const float4 p0 = xyz4[b * NRAW];       // first keypoint = original idx 0
  float lx = p0.x, ly = p0.y, lz = p0.z;
  if (t == 0) { kx[b * NKP] = lx; ky[b * NKP] = ly; kz[b * NKP] = lz; }

  unsigned long long cpk = 0ULL;          // cached (val<<32 | ~minidx)
  float bvc = __builtin_inff();           // cached wave max dd (inf: no skip)
  __syncthreads();

  for (int s = 1; s < NKP; ++s) {
    // conservative lower bound of d2 from center to any point of this wave
    float dxm = fmaxf(fmaxf(bnx - lx, lx - bxx), 0.f);
    float dym = fmaxf(fmaxf(bny - ly, ly - bxy), 0.f);
    float dzm = fmaxf(fmaxf(bnz - lz, lz - bxz), 0.f);
    const float LB2 = dxm * dxm + dym * dym + dzm * dzm;
    if (!(LB2 * 0.9999f > bvc)) {         // active
#pragma unroll
      for (int j = 0; j < 16; ++j) {
        float dx = px[j] - lx, dy = py[j] - ly, dz = pz[j] - lz;
        float d2 = dx * dx; d2 = d2 + dy * dy; d2 = d2 + dz * dz;
        dd[j] = fminf(dd[j], d2);
      }
      float m8[8];
#pragma unroll
      for (int j = 0; j < 8; ++j) m8[j] = fmaxf(dd[2 * j], dd[2 * j + 1]);
      float m4[4];
#pragma unroll
      for (int j = 0; j < 4; ++j) m4[j] = fmaxf(m8[2 * j], m8[2 * j + 1]);
      const float bv = fmaxf(fmaxf(m4[0], m4[1]), fmaxf(m4[2], m4[3]));

      const unsigned vb = __float_as_uint(bv);
      const unsigned wmax =
          (unsigned)__builtin_amdgcn_readlane((int)wave_umax63(vb), 63);
      unsigned mo = 0xFFFFFFFFu;
      if (vb == wmax) {                   // >=1 lane per wave; others skip
#pragma unroll
        for (int j = 0; j < 16; ++j)
          if (__float_as_uint(dd[j]) == wmax) {
            const unsigned o = (unsigned)perm[wb + j * 64 + lane];
            mo = o < mo ? o : mo;
          }
      }
      const unsigned cand = (vb == wmax) ? ~mo : 0u;
      const unsigned cm =
          (unsigned)__builtin_amdgcn_readlane((int)wave_umax63(cand), 63);
      cpk = ((unsigned long long)wmax << 32) | (unsigned long long)cm;
      bvc = __uint_as_float(wmax);
    }
    if (lane == 63) atomicMax(&slot[s % 3], cpk);
    __syncthreads();

    const unsigned long long g = slot[s % 3];
    const int wi = __builtin_amdgcn_readfirstlane((int)~(unsigned)g);
    if (t == 0) slot[(s + 2) % 3] = 0ULL;     // next used at iter s+2
    const float4 cw = xyz4[b * NRAW + wi];    // uniform -> s_load_dwordx4
    lx = cw.x; ly = cw.y; lz = cw.z;
    if (t == 0) { kx[b * NKP + s] = lx; ky[b * NKP + s] = ly; kz[b * NKP + s] = lz; }
  }
}

// ---------------------------------------------------------------------------
// K2: BEV bilinear. one block per keypoint, 256 threads = 256 channels.
// ---------------------------------------------------------------------------
__global__ __launch_bounds__(256) void bev_kernel(
    const float* __restrict__ sf, const float* __restrict__ kx,
    const float* __restrict__ ky, float* __restrict__ feats) {
#pragma clang fp contract(off)
  const int kidx = blockIdx.x;
  const int c = threadIdx.x;
  const int b = kidx >> 11;
  const float x = (kx[kidx] - 0.0f) / 0.05f / 8.0f;
  const float y = (ky[kidx] - (-40.0f)) / 0.05f / 8.0f;
  const float xf = floorf(x), yf = floorf(y);
  int x0 = (int)xf;     x0 = x0 < 0 ? 0 : (x0 > 175 ? 175 : x0);
  int x1 = (int)xf + 1; x1 = x1 < 0 ? 0 : (x1 > 175 ? 175 : x1);
  int y0 = (int)yf;     y0 = y0 < 0 ? 0 : (y0 > 199 ? 199 : y0);
  int y1 = (int)yf + 1; y1 = y1 < 0 ? 0 : (y1 > 199 ? 199 : y1);
  const float x0f = (float)x0, x1f = (float)x1, y0f = (float)y0, y1f = (float)y1;
  const float wa = (x - x0f) * (y1f - y);
  const float wb = (x1f - x) * (y1f - y);
  const float wc = (x1f - x) * (y - y0f);
  const float wd = (x - x0f) * (y - y0f);
  const float* base = sf + ((size_t)b * 256 + c) * (200 * 176);
  const float fa = base[y1 * 176 + x0];
  const float fb = base[y1 * 176 + x1];
  const float fc = base[y0 * 176 + x1];
  const float fd = base[y0 * 176 + x0];
  float r = fd * wb; r = r + fc * wa; r = r + fa * wc; r = r + fb * wd;
  feats[(size_t)kidx * 416 + c] = r;
}

// ---------------------------------------------------------------------------
// K3: raw SA. one wave per (keypoint, radius). MLP 4->16->16, max-pool.
// Uses ORIGINAL-order xyz4 (ball query keeps first-16-by-original-index).
// ---------------------------------------------------------------------------
__global__ __launch_bounds__(256) void raw_sa_kernel(
    const float4* __restrict__ xyz4,
    const float* __restrict__ kx, const float* __restrict__ ky,
    const float* __restrict__ kz,
    const float* __restrict__ w0, const float* __restrict__ g0,
    const float* __restrict__ b0, const float* __restrict__ w1,
    const float* __restrict__ g1, const float* __restrict__ b1,
    float* __restrict__ feats) {
  const int wv = threadIdx.x >> 6;
  const int lane = threadIdx.x & 63;
  const int gw = blockIdx.x * 4 + wv;       // 0..8191
  const int ri = gw >> 12;                  // radius index 0/1
  const int kidx = gw & 4095;
  const int b = kidx >> 11;
  const float R2 = ri ? (float)(0.8 * 0.8) : (float)(0.4 * 0.4);

  __shared__ int   idxl[4][16];
  __shared__ float hbuf[4][16][17];

  const float kxv = kx[kidx], kyv = ky[kidx], kzv = kz[kidx];
  const int base = b * NRAW;
  int cnt = 0;
  {
#pragma clang fp contract(off)
    for (int ch = 0; ch < NRAW / 64 && cnt < 16; ++ch) {
      const float4 q = xyz4[base + ch * 64 + lane];
      float dx = kxv - q.x, dy = kyv - q.y, dz = kzv - q.z;
      float d2 = dx * dx; d2 = d2 + dy * dy; d2 = d2 + dz * dz;
      unsigned long long m = __ballot(d2 < R2);
      while (m && cnt < 16) {
        int bit = __builtin_ctzll(m);
        if (lane == 0) idxl[wv][cnt] = ch * 64 + bit;
        ++cnt;
        m &= m - 1;
      }
    }
  }
  const int outoff = kidx * 416 + 256 + ri * 16;
  if (cnt == 0) {
    if (lane < 16) feats[outoff + lane] = 0.f;
    return;
  }
  __threadfence_block();

  const int s = lane & 15, cq = lane >> 4;
  const int ss = (s < cnt) ? s : 0;          // duplicate sample 0 (matches ref pad)
  const float4 q = xyz4[base + idxl[wv][ss]];
  const float gx = q.x - kxv, gy = q.y - kyv, gz = q.z - kzv, gi = q.w;
  const int wb0 = ri * 64, cb = ri * 16;
#pragma unroll
  for (int j = 0; j < 4; ++j) {
    int c = cq * 4 + j;
    float a = gx * w0[wb0 + c];
    a = fmaf(gy, w0[wb0 + 16 + c], a);
    a = fmaf(gz, w0[wb0 + 32 + c], a);
    a = fmaf(gi, w0[wb0 + 48 + c], a);
    a = fmaf(a, g0[cb + c] * kBNS, b0[cb + c]);
    hbuf[wv][s][c] = fmaxf(a, 0.f);
  }
  __threadfence_block();
  float o0 = 0.f, o1 = 0.f, o2 = 0.f, o3 = 0.f;
  const int wb1 = ri * 256;
#pragma unroll
  for (int k = 0; k < 16; ++k) {
    float hk = hbuf[wv][s][k];
    o0 = fmaf(hk, w1[wb1 + k * 16 + cq * 4 + 0], o0);
    o1 = fmaf(hk, w1[wb1 + k * 16 + cq * 4 + 1], o1);
    o2 = fmaf(hk, w1[wb1 + k * 16 + cq * 4 + 2], o2);
    o3 = fmaf(hk, w1[wb1 + k * 16 + cq * 4 + 3], o3);
  }
  float v0 = fmaxf(fmaf(o0, g1[cb + cq * 4 + 0] * kBNS, b1[cb + cq * 4 + 0]), 0.f);
  float v1 = fmaxf(fmaf(o1, g1[cb + cq * 4 + 1] * kBNS, b1[cb + cq * 4 + 1]), 0.f);
  float v2 = fmaxf(fmaf(o2, g1[cb + cq * 4 + 2] * kBNS, b1[cb + cq * 4 + 2]), 0.f);
  float v3 = fmaxf(fmaf(o3, g1[cb + cq * 4 + 3] * kBNS, b1[cb + cq * 4 + 3]), 0.f);
#pragma unroll
  for (int off = 1; off < 16; off <<= 1) {
    v0 = fmaxf(v0, __shfl_xor(v0, off, 64));
    v1 = fmaxf(v1, __shfl_xor(v1, off, 64));
    v2 = fmaxf(v2, __shfl_xor(v2, off, 64));
    v3 = fmaxf(v3, __shfl_xor(v3, off, 64));
  }
  if (s == 0) {
    feats[outoff + cq * 4 + 0] = v0;
    feats[outoff + cq * 4 + 1] = v1;
    feats[outoff + cq * 4 + 2] = v2;
    feats[outoff + cq * 4 + 3] = v3;
  }
}

// ---------------------------------------------------------------------------
// K4: conv SA. one wave per (keypoint, radius). MLP 67->64->64, max-pool.
// ---------------------------------------------------------------------------
__global__ __launch_bounds__(256) void conv_sa_kernel(
    const float4* __restrict__ cxyz4, const float* __restrict__ vf,
    const float* __restrict__ kx, const float* __restrict__ ky,
    const float* __restrict__ kz,
    const float* __restrict__ w0, const float* __restrict__ g0,
    const float* __restrict__ b0, const float* __restrict__ w1,
    const float* __restrict__ g1, const float* __restrict__ b1,
    float* __restrict__ feats) {
  const int wv = threadIdx.x >> 6;
  const int lane = threadIdx.x & 63;
  const int gw = blockIdx.x * 4 + wv;
  const int ri = gw >> 12;
  const int kidx = gw & 4095;
  const int b = kidx >> 11;
  const int NS = ri ? 32 : 16;
  const float R2 = ri ? (float)(2.4 * 2.4) : (float)(1.2 * 1.2);

  __shared__ int   idxl[4][32];
  __shared__ float gbuf[4][64];
  __shared__ float hbuf[4][32][64];

  const float kxv = kx[kidx], kyv = ky[kidx], kzv = kz[kidx];
  const int base = b * MVOX;
  int cnt = 0;
  {
#pragma clang fp contract(off)
    for (int ch = 0; ch < MVOX / 64 && cnt < NS; ++ch) {
      const float4 q = cxyz4[base + ch * 64 + lane];
      float dx = kxv - q.x, dy = kyv - q.y, dz = kzv - q.z;
      float d2 = dx * dx; d2 = d2 + dy * dy; d2 = d2 + dz * dz;
      unsigned long long m = __ballot(d2 < R2);
      while (m && cnt < NS) {
        int bit = __builtin_ctzll(m);
        if (lane == 0) idxl[wv][cnt] = ch * 64 + bit;
        ++cnt;
        m &= m - 1;
      }
    }
  }
  const int outoff = kidx * 416 + 288 + ri * 64;
  if (cnt == 0) {
    feats[outoff + lane] = 0.f;
    return;
  }
  __threadfence_block();

  // per-lane weight columns (lane == output channel)
  const float wA0 = w0[(ri * 67 + 0) * 64 + lane];
  const float wA1 = w0[(ri * 67 + 1) * 64 + lane];
  const float wA2 = w0[(ri * 67 + 2) * 64 + lane];
  float wB[64];
#pragma unroll
  for (int k = 0; k < 64; ++k) wB[k] = w0[(ri * 67 + 3 + k) * 64 + lane];
  float wC[64];
#pragma unroll
  for (int k = 0; k < 64; ++k) wC[k] = w1[(ri * 64 + k) * 64 + lane];
  const float s0 = g0[ri * 64 + lane] * kBNS, bb0 = b0[ri * 64 + lane];
  const float s1 = g1[ri * 64 + lane] * kBNS, bb1 = b1[ri * 64 + lane];

  for (int sm = 0; sm < cnt; ++sm) {
    const int p = base + idxl[wv][sm];
    const float4 q = cxyz4[p];
    const float ox = q.x - kxv, oy = q.y - kyv, oz = q.z - kzv;
    gbuf[wv][lane] = vf[(size_t)p * 64 + lane];
    __threadfence_block();
    float acc = ox * wA0;
    acc = fmaf(oy, wA1, acc);
    acc = fmaf(oz, wA2, acc);
#pragma unroll
    for (int k4 = 0; k4 < 16; ++k4) {
      float4 g4 = *(const float4*)&gbuf[wv][k4 * 4];
      acc = fmaf(g4.x, wB[k4 * 4 + 0], acc);
      acc = fmaf(g4.y, wB[k4 * 4 + 1], acc);
      acc = fmaf(g4.z, wB[k4 * 4 + 2], acc);
      acc = fmaf(g4.w, wB[k4 * 4 + 3], acc);
    }
    hbuf[wv][sm][lane] = fmaxf(fmaf(acc, s0, bb0), 0.f);
    __threadfence_block();
  }
  float mx = -1e30f;
  for (int sm = 0; sm < cnt; ++sm) {
    float acc = 0.f;
#pragma unroll
    for (int k4 = 0; k4 < 16; ++k4) {
      float4 h4 = *(const float4*)&hbuf[wv][sm][k4 * 4];
      acc = fmaf(h4.x, wC[k4 * 4 + 0], acc);
      acc = fmaf(h4.y, wC[k4 * 4 + 1], acc);
      acc = fmaf(h4.z, wC[k4 * 4 + 2], acc);
      acc = fmaf(h4.w, wC[k4 * 4 + 3], acc);
    }
    mx = fmaxf(mx, fmaxf(fmaf(acc, s1, bb1), 0.f));
  }
  feats[outoff + lane] = mx;
}

// ---------------------------------------------------------------------------
// K5: fusion 416 -> 128 + BN + ReLU. one thread per (kp, out-channel).
// ---------------------------------------------------------------------------
__global__ __launch_bounds__(256) void fusion_kernel(
    const float* __restrict__ feats, const float* __restrict__ fw,
    const float* __restrict__ fg, const float* __restrict__ fb,
    float* __restrict__ out) {
  const int gid = blockIdx.x * 256 + threadIdx.x;
  const int kidx = gid >> 7, c = gid & 127;
  const float* f = feats + (size_t)kidx * 416;
  float acc = 0.f;
#pragma unroll 4
  for (int k = 0; k < 416; k += 4) {
    float4 fv = *(const float4*)(f + k);
    acc = fmaf(fv.x, fw[(k + 0) * 128 + c], acc);
    acc = fmaf(fv.y, fw[(k + 1) * 128 + c], acc);
    acc = fmaf(fv.z, fw[(k + 2) * 128 + c], acc);
    acc = fmaf(fv.w, fw[(k + 3) * 128 + c], acc);
  }
  out[gid] = fmaxf(fmaf(acc, fg[c] * kBNS, fb[c]), 0.f);
}

// ---------------------------------------------------------------------------
extern "C" void kernel_launch(void* const* d_in, const int* in_sizes, int n_in,
                              void* d_out, int out_size, void* d_ws, size_t ws_size,
                              hipStream_t stream) {
  (void)in_sizes; (void)n_in; (void)out_size; (void)ws_size;
  const float* pts = (const float*)d_in[0];
  const float* sf  = (const float*)d_in[1];
  const int*   vc  = (const int*)d_in[2];
  const float* vf  = (const float*)d_in[3];
  const float* raw_w0 = (const float*)d_in[4];
  const float* raw_g0 = (const float*)d_in[5];
  const float* raw_b0 = (const float*)d_in[6];
  const float* raw_w1 = (const float*)d_in[7];
  const float* raw_g1 = (const float*)d_in[8];
  const float* raw_b1 = (const float*)d_in[9];
  const float* conv_w0 = (const float*)d_in[10];
  const float* conv_g0 = (const float*)d_in[11];
  const float* conv_b0 = (const float*)d_in[12];
  const float* conv_w1 = (const float*)d_in[13];
  const float* conv_g1 = (const float*)d_in[14];
  const float* conv_b1 = (const float*)d_in[15];
  const float* fus_w = (const float*)d_in[16];
  const float* fus_g = (const float*)d_in[17];
  const float* fus_b = (const float*)d_in[18];
  float* out = (float*)d_out;

  float* W = (float*)d_ws;
  float4* xyz4  = (float4*)W;             // 32768 float4 = 131072 floats
  float4* cxyz4 = (float4*)(W + 131072);  // 16384 float4 = 65536 floats
  float* kx    = W + 196608;              // 4096 each
  float* ky    = W + 200704;
  float* kz    = W + 204800;
  float* feats = W + 208896;              // 4096 * 416
  // fps-only scratch ALIASED into the feats region (fps completes before any
  // feats writes): sorted coords + perm
  float4* sx4   = (float4*)(W + 208896);          // 131072 floats
  int*    sperm = (int*)(W + 208896 + 131072);    // 32768 ints

  prep_kernel<<<128, 256, 0, stream>>>(pts, vc, xyz4, cxyz4);
  sort_kernel<<<2, 1024, 0, stream>>>(pts, sx4, sperm);
  fps_kernel<<<2, 1024, 0, stream>>>(sx4, sperm, xyz4, kx, ky, kz);
  bev_kernel<<<NKPALL, 256, 0, stream>>>(sf, kx, ky, feats);
  raw_sa_kernel<<<2048, 256, 0, stream>>>(xyz4, kx, ky, kz,
                                          raw_w0, raw_g0, raw_b0, raw_w1, raw_g1, raw_b1,
                                          feats);
  conv_sa_kernel<<<2048, 256, 0, stream>>>(cxyz4, vf, kx, ky, kz,
                                           conv_w0, conv_g0, conv_b0, conv_w1, conv_g1, conv_b1,
                                           feats);
  fusion_kernel<<<2048, 256, 0, stream>>>(feats, fus_w, fus_g, fus_b, out);
}

// Round 8
// 2370.911 us; speedup vs baseline: 1.7555x; 1.2308x over previous
//
#include <hip/hip_runtime.h>

// ---------------------------------------------------------------------------
// VoxelSetAbstraction forward (PV-RCNN style) for MI355X
//   B=2, N_RAW=16384, N_KP=2048, M_VOX=8192, C_VOX=64
//   BEV: (2,256,200,176), stride 8, voxel 0.05, pc_min (0,-40,-3)
//   raw SA: radii (0.4,0.8) ns (16,16), MLP 4->16->16
//   conv SA: radii (1.2,2.4) ns (16,32), MLP 67->64->64
//   fusion: 416 -> 128
// ---------------------------------------------------------------------------

#define NRAW   16384
#define MVOX   8192
#define NKP    2048
#define NKPALL 4096   // B * NKP

__device__ __constant__ float kBNS = (float)0.9999950000374997; // 1/sqrt(1+1e-5)

// ---------------------------------------------------------------------------
// K0: pack points to interleaved float4 (x,y,z,intensity) + voxel centers
// ---------------------------------------------------------------------------
__global__ __launch_bounds__(256) void prep_kernel(
    const float* __restrict__ pts, const int* __restrict__ vc,
    float4* __restrict__ xyz4, float4* __restrict__ cxyz4) {
#pragma clang fp contract(off)
  int i = blockIdx.x * 256 + threadIdx.x;
  if (i < 2 * NRAW) {
    const float* p = pts + (size_t)i * 5;
    xyz4[i] = make_float4(p[1], p[2], p[3], p[4]);
  }
  if (i < 2 * MVOX) {
    const int* v = vc + (size_t)i * 4;
    cxyz4[i] = make_float4(((float)v[3] + 0.5f) * 0.2f + 0.0f,
                           ((float)v[2] + 0.5f) * 0.2f + -40.0f,
                           ((float)v[1] + 0.5f) * 0.4f + -3.0f, 0.f);
  }
}

// ---------------------------------------------------------------------------
// K0b: y-histogram sort (256 bins) per batch -> sperm only (sorted-pos ->
// original local index). FPS gathers coords from xyz4 via sperm, which also
// warms the fps block's local L2 with the whole xyz4 batch (the per-iter
// winner s_load then hits local L2 instead of a ~500cyc L3/other-XCD trip —
// r7 FETCH_SIZE 543KB showed those misses). Bin-internal order is
// nondeterministic (atomic ranks) but FPS output is order-invariant: ties
// are resolved by ORIGINAL index carried in registers.
// ---------------------------------------------------------------------------
__global__ __launch_bounds__(1024) void sort_kernel(
    const float* __restrict__ pts, int* __restrict__ sperm) {
  const int b = blockIdx.x, t = threadIdx.x;
  __shared__ unsigned hist[256], cur[256];
  if (t < 256) hist[t] = 0u;
  __syncthreads();
  int bins[16];
#pragma unroll
  for (int k = 0; k < 16; ++k) {
    const int i = k * 1024 + t;
    const float y = pts[(size_t)(b * NRAW + i) * 5 + 2];
    int bin = (int)((y + 40.0f) * 3.2f);
    bin = bin < 0 ? 0 : (bin > 255 ? 255 : bin);
    bins[k] = bin;
    atomicAdd(&hist[bin], 1u);
  }
  __syncthreads();
  if (t == 0) {
    unsigned acc = 0;
    for (int i = 0; i < 256; ++i) { cur[i] = acc; acc += hist[i]; }
  }
  __syncthreads();
#pragma unroll
  for (int k = 0; k < 16; ++k) {
    const int i = k * 1024 + t;
    const unsigned pos = atomicAdd(&cur[bins[k]], 1u);
    sperm[b * NRAW + pos] = i;
  }
}

// ---------------------------------------------------------------------------
// Wave-wide u32 max via DPP (VALU pipe, zero DS). Lane 63 holds the result.
// ---------------------------------------------------------------------------
__device__ __forceinline__ unsigned wave_umax63(unsigned v) {
  unsigned t;
  t = (unsigned)__builtin_amdgcn_update_dpp(0, (int)v, 0xB1,  0xf, 0xf, true); v = v < t ? t : v;
  t = (unsigned)__builtin_amdgcn_update_dpp(0, (int)v, 0x4E,  0xf, 0xf, true); v = v < t ? t : v;
  t = (unsigned)__builtin_amdgcn_update_dpp(0, (int)v, 0x124, 0xf, 0xf, true); v = v < t ? t : v;
  t = (unsigned)__builtin_amdgcn_update_dpp(0, (int)v, 0x128, 0xf, 0xf, true); v = v < t ? t : v;
  t = (unsigned)__builtin_amdgcn_update_dpp(0, (int)v, 0x142, 0xa, 0xf, true); v = v < t ? t : v;
  t = (unsigned)__builtin_amdgcn_update_dpp(0, (int)v, 0x143, 0xc, 0xf, true); v = v < t ? t : v;
  return v;  // valid in lane 63
}

// ---------------------------------------------------------------------------
// K1: farthest point sampling with EXACT bbox pruning (r7) minus its two
// tail taxes: perm lives in registers pj[16] (no 64KB LDS array, no
// ds_reads on the argmax scan) and the init gather of xyz4 warms local L2
// so the winner s_load stops missing.
// Per iteration (one barrier, slot triple-buffered as r7):
//   skip: LB2(center, wave bbox) * 0.9999 > cached wave max -> re-post cache
//   active: dd=min(dd,d2) exact numpy order; fmax tree; DPP wave max;
//     tied lanes reg-scan pj for min ORIGINAL idx; DPP min-idx; cache pk.
//   lane63 ds atomicMax(slot[s%3], pk); barrier; read slot; s_load coords.
// ---------------------------------------------------------------------------
__global__ __launch_bounds__(1024, 4) void fps_kernel(
    const int* __restrict__ sperm, const float4* __restrict__ xyz4,
    float* __restrict__ kx, float* __restrict__ ky, float* __restrict__ kz) {
#pragma clang fp contract(off)
  const int b = blockIdx.x;
  const int t = threadIdx.x;
  const int w = t >> 6, lane = t & 63;
  const int wb = w * 1024;
  const int base = b * NRAW;

  __shared__ unsigned long long slot[3];

  int pj[16];
  float px[16], py[16], pz[16], dd[16];
#pragma unroll
  for (int j = 0; j < 16; ++j)
    pj[j] = sperm[base + wb + j * 64 + lane];
#pragma unroll
  for (int j = 0; j < 16; ++j) {
    const float4 q = xyz4[base + pj[j]];   // gather; warms local L2 with batch
    px[j] = q.x; py[j] = q.y; pz[j] = q.z; dd[j] = 1e10f;
  }
  if (t < 3) slot[t] = 0ULL;

  // wave bbox (one-time): per-lane min/max then 6-stage shuffle reduce
  float bnx = px[0], bxx = px[0], bny = py[0], bxy = py[0], bnz = pz[0], bxz = pz[0];
#pragma unroll
  for (int j = 1; j < 16; ++j) {
    bnx = fminf(bnx, px[j]); bxx = fmaxf(bxx, px[j]);
    bny = fminf(bny, py[j]); bxy = fmaxf(bxy, py[j]);
    bnz = fminf(bnz, pz[j]); bxz = fmaxf(bxz, pz[j]);
  }
#pragma unroll
  for (int off = 1; off < 64; off <<= 1) {
    bnx = fminf(bnx, __shfl_xor(bnx, off, 64));
    bxx = fmaxf(bxx, __shfl_xor(bxx, off, 64));
    bny = fminf(bny, __shfl_xor(bny, off, 64));
    bxy = fmaxf(bxy, __shfl_xor(bxy, off, 64));
    bnz = fminf(bnz, __shfl_xor(bnz, off, 64));
    bxz = fmaxf(bxz, __shfl_xor(bxz, off, 64));
  }

  const float4 p0 = xyz4[base];           // first keypoint = original idx 0
  float lx = p0.x, ly = p0.y, lz = p0.z;
  if (t == 0) { kx[b * NKP] = lx; ky[b * NKP] = ly; kz[b * NKP] = lz; }

  unsigned long long cpk = 0ULL;          // cached (val<<32 | ~minidx)
  float bvc = __builtin_inff();           // cached wave max dd (inf: no skip)
  __syncthreads();

  for (int s = 1; s < NKP; ++s) {
    // conservative lower bound of d2 from center to any point of this wave
    float dxm = fmaxf(fmaxf(bnx - lx, lx - bxx), 0.f);
    float dym = fmaxf(fmaxf(bny - ly, ly - bxy), 0.f);
    float dzm = fmaxf(fmaxf(bnz - lz, lz - bxz), 0.f);
    const float LB2 = dxm * dxm + dym * dym + dzm * dzm;
    if (!(LB2 * 0.9999f > bvc)) {         // active
#pragma unroll
      for (int j = 0; j < 16; ++j) {
        float dx = px[j] - lx, dy = py[j] - ly, dz = pz[j] - lz;
        float d2 = dx * dx; d2 = d2 + dy * dy; d2 = d2 + dz * dz;
        dd[j] = fminf(dd[j], d2);
      }
      float m8[8];
#pragma unroll
      for (int j = 0; j < 8; ++j) m8[j] = fmaxf(dd[2 * j], dd[2 * j + 1]);
      float m4[4];
#pragma unroll
      for (int j = 0; j < 4; ++j) m4[j] = fmaxf(m8[2 * j], m8[2 * j + 1]);
      const float bv = fmaxf(fmaxf(m4[0], m4[1]), fmaxf(m4[2], m4[3]));

      const unsigned vb = __float_as_uint(bv);
      const unsigned wmax =
          (unsigned)__builtin_amdgcn_readlane((int)wave_umax63(vb), 63);
      unsigned mo = 0xFFFFFFFFu;
      if (vb == wmax) {                   // tied lanes only; pure VALU scan
#pragma unroll
        for (int j = 0; j < 16; ++j)
          if (__float_as_uint(dd[j]) == wmax) {
            const unsigned o = (unsigned)pj[j];
            mo = o < mo ? o : mo;
          }
      }
      const unsigned cand = (vb == wmax) ? ~mo : 0u;
      const unsigned cm =
          (unsigned)__builtin_amdgcn_readlane((int)wave_umax63(cand), 63);
      cpk = ((unsigned long long)wmax << 32) | (unsigned long long)cm;
      bvc = __uint_as_float(wmax);
    }
    if (lane == 63) atomicMax(&slot[s % 3], cpk);
    __syncthreads();

    const unsigned long long g = slot[s % 3];
    const int wi = __builtin_amdgcn_readfirstlane((int)~(unsigned)g);
    if (t == 0) slot[(s + 2) % 3] = 0ULL;     // next used at iter s+2
    const float4 cw = xyz4[base + wi];        // uniform s_load, L2-warm
    lx = cw.x; ly = cw.y; lz = cw.z;
    if (t == 0) { kx[b * NKP + s] = lx; ky[b * NKP + s] = ly; kz[b * NKP + s] = lz; }
  }
}

// ---------------------------------------------------------------------------
// K2: BEV bilinear. one block per keypoint, 256 threads = 256 channels.
// ---------------------------------------------------------------------------
__global__ __launch_bounds__(256) void bev_kernel(
    const float* __restrict__ sf, const float* __restrict__ kx,
    const float* __restrict__ ky, float* __restrict__ feats) {
#pragma clang fp contract(off)
  const int kidx = blockIdx.x;
  const int c = threadIdx.x;
  const int b = kidx >> 11;
  const float x = (kx[kidx] - 0.0f) / 0.05f / 8.0f;
  const float y = (ky[kidx] - (-40.0f)) / 0.05f / 8.0f;
  const float xf = floorf(x), yf = floorf(y);
  int x0 = (int)xf;     x0 = x0 < 0 ? 0 : (x0 > 175 ? 175 : x0);
  int x1 = (int)xf + 1; x1 = x1 < 0 ? 0 : (x1 > 175 ? 175 : x1);
  int y0 = (int)yf;     y0 = y0 < 0 ? 0 : (y0 > 199 ? 199 : y0);
  int y1 = (int)yf + 1; y1 = y1 < 0 ? 0 : (y1 > 199 ? 199 : y1);
  const float x0f = (float)x0, x1f = (float)x1, y0f = (float)y0, y1f = (float)y1;
  const float wa = (x - x0f) * (y1f - y);
  const float wb = (x1f - x) * (y1f - y);
  const float wc = (x1f - x) * (y - y0f);
  const float wd = (x - x0f) * (y - y0f);
  const float* base = sf + ((size_t)b * 256 + c) * (200 * 176);
  const float fa = base[y1 * 176 + x0];
  const float fb = base[y1 * 176 + x1];
  const float fc = base[y0 * 176 + x1];
  const float fd = base[y0 * 176 + x0];
  float r = fd * wb; r = r + fc * wa; r = r + fa * wc; r = r + fb * wd;
  feats[(size_t)kidx * 416 + c] = r;
}

// ---------------------------------------------------------------------------
// K3: raw SA. one wave per (keypoint, radius). MLP 4->16->16, max-pool.
// Uses ORIGINAL-order xyz4 (ball query keeps first-16-by-original-index).
// ---------------------------------------------------------------------------
__global__ __launch_bounds__(256) void raw_sa_kernel(
    const float4* __restrict__ xyz4,
    const float* __restrict__ kx, const float* __restrict__ ky,
    const float* __restrict__ kz,
    const float* __restrict__ w0, const float* __restrict__ g0,
    const float* __restrict__ b0, const float* __restrict__ w1,
    const float* __restrict__ g1, const float* __restrict__ b1,
    float* __restrict__ feats) {
  const int wv = threadIdx.x >> 6;
  const int lane = threadIdx.x & 63;
  const int gw = blockIdx.x * 4 + wv;       // 0..8191
  const int ri = gw >> 12;                  // radius index 0/1
  const int kidx = gw & 4095;
  const int b = kidx >> 11;
  const float R2 = ri ? (float)(0.8 * 0.8) : (float)(0.4 * 0.4);

  __shared__ int   idxl[4][16];
  __shared__ float hbuf[4][16][17];

  const float kxv = kx[kidx], kyv = ky[kidx], kzv = kz[kidx];
  const int base = b * NRAW;
  int cnt = 0;
  {
#pragma clang fp contract(off)
    for (int ch = 0; ch < NRAW / 64 && cnt < 16; ++ch) {
      const float4 q = xyz4[base + ch * 64 + lane];
      float dx = kxv - q.x, dy = kyv - q.y, dz = kzv - q.z;
      float d2 = dx * dx; d2 = d2 + dy * dy; d2 = d2 + dz * dz;
      unsigned long long m = __ballot(d2 < R2);
      while (m && cnt < 16) {
        int bit = __builtin_ctzll(m);
        if (lane == 0) idxl[wv][cnt] = ch * 64 + bit;
        ++cnt;
        m &= m - 1;
      }
    }
  }
  const int outoff = kidx * 416 + 256 + ri * 16;
  if (cnt == 0) {
    if (lane < 16) feats[outoff + lane] = 0.f;
    return;
  }
  __threadfence_block();

  const int s = lane & 15, cq = lane >> 4;
  const int ss = (s < cnt) ? s : 0;          // duplicate sample 0 (matches ref pad)
  const float4 q = xyz4[base + idxl[wv][ss]];
  const float gx = q.x - kxv, gy = q.y - kyv, gz = q.z - kzv, gi = q.w;
  const int wb0 = ri * 64, cb = ri * 16;
#pragma unroll
  for (int j = 0; j < 4; ++j) {
    int c = cq * 4 + j;
    float a = gx * w0[wb0 + c];
    a = fmaf(gy, w0[wb0 + 16 + c], a);
    a = fmaf(gz, w0[wb0 + 32 + c], a);
    a = fmaf(gi, w0[wb0 + 48 + c], a);
    a = fmaf(a, g0[cb + c] * kBNS, b0[cb + c]);
    hbuf[wv][s][c] = fmaxf(a, 0.f);
  }
  __threadfence_block();
  float o0 = 0.f, o1 = 0.f, o2 = 0.f, o3 = 0.f;
  const int wb1 = ri * 256;
#pragma unroll
  for (int k = 0; k < 16; ++k) {
    float hk = hbuf[wv][s][k];
    o0 = fmaf(hk, w1[wb1 + k * 16 + cq * 4 + 0], o0);
    o1 = fmaf(hk, w1[wb1 + k * 16 + cq * 4 + 1], o1);
    o2 = fmaf(hk, w1[wb1 + k * 16 + cq * 4 + 2], o2);
    o3 = fmaf(hk, w1[wb1 + k * 16 + cq * 4 + 3], o3);
  }
  float v0 = fmaxf(fmaf(o0, g1[cb + cq * 4 + 0] * kBNS, b1[cb + cq * 4 + 0]), 0.f);
  float v1 = fmaxf(fmaf(o1, g1[cb + cq * 4 + 1] * kBNS, b1[cb + cq * 4 + 1]), 0.f);
  float v2 = fmaxf(fmaf(o2, g1[cb + cq * 4 + 2] * kBNS, b1[cb + cq * 4 + 2]), 0.f);
  float v3 = fmaxf(fmaf(o3, g1[cb + cq * 4 + 3] * kBNS, b1[cb + cq * 4 + 3]), 0.f);
#pragma unroll
  for (int off = 1; off < 16; off <<= 1) {
    v0 = fmaxf(v0, __shfl_xor(v0, off, 64));
    v1 = fmaxf(v1, __shfl_xor(v1, off, 64));
    v2 = fmaxf(v2, __shfl_xor(v2, off, 64));
    v3 = fmaxf(v3, __shfl_xor(v3, off, 64));
  }
  if (s == 0) {
    feats[outoff + cq * 4 + 0] = v0;
    feats[outoff + cq * 4 + 1] = v1;
    feats[outoff + cq * 4 + 2] = v2;
    feats[outoff + cq * 4 + 3] = v3;
  }
}

// ---------------------------------------------------------------------------
// K4: conv SA. one wave per (keypoint, radius). MLP 67->64->64, max-pool.
// ---------------------------------------------------------------------------
__global__ __launch_bounds__(256) void conv_sa_kernel(
    const float4* __restrict__ cxyz4, const float* __restrict__ vf,
    const float* __restrict__ kx, const float* __restrict__ ky,
    const float* __restrict__ kz,
    const float* __restrict__ w0, const float* __restrict__ g0,
    const float* __restrict__ b0, const float* __restrict__ w1,
    const float* __restrict__ g1, const float* __restrict__ b1,
    float* __restrict__ feats) {
  const int wv = threadIdx.x >> 6;
  const int lane = threadIdx.x & 63;
  const int gw = blockIdx.x * 4 + wv;
  const int ri = gw >> 12;
  const int kidx = gw & 4095;
  const int b = kidx >> 11;
  const int NS = ri ? 32 : 16;
  const float R2 = ri ? (float)(2.4 * 2.4) : (float)(1.2 * 1.2);

  __shared__ int   idxl[4][32];
  __shared__ float gbuf[4][64];
  __shared__ float hbuf[4][32][64];

  const float kxv = kx[kidx], kyv = ky[kidx], kzv = kz[kidx];
  const int base = b * MVOX;
  int cnt = 0;
  {
#pragma clang fp contract(off)
    for (int ch = 0; ch < MVOX / 64 && cnt < NS; ++ch) {
      const float4 q = cxyz4[base + ch * 64 + lane];
      float dx = kxv - q.x, dy = kyv - q.y, dz = kzv - q.z;
      float d2 = dx * dx; d2 = d2 + dy * dy; d2 = d2 + dz * dz;
      unsigned long long m = __ballot(d2 < R2);
      while (m && cnt < NS) {
        int bit = __builtin_ctzll(m);
        if (lane == 0) idxl[wv][cnt] = ch * 64 + bit;
        ++cnt;
        m &= m - 1;
      }
    }
  }
  const int outoff = kidx * 416 + 288 + ri * 64;
  if (cnt == 0) {
    feats[outoff + lane] = 0.f;
    return;
  }
  __threadfence_block();

  // per-lane weight columns (lane == output channel)
  const float wA0 = w0[(ri * 67 + 0) * 64 + lane];
  const float wA1 = w0[(ri * 67 + 1) * 64 + lane];
  const float wA2 = w0[(ri * 67 + 2) * 64 + lane];
  float wB[64];
#pragma unroll
  for (int k = 0; k < 64; ++k) wB[k] = w0[(ri * 67 + 3 + k) * 64 + lane];
  float wC[64];
#pragma unroll
  for (int k = 0; k < 64; ++k) wC[k] = w1[(ri * 64 + k) * 64 + lane];
  const float s0 = g0[ri * 64 + lane] * kBNS, bb0 = b0[ri * 64 + lane];
  const float s1 = g1[ri * 64 + lane] * kBNS, bb1 = b1[ri * 64 + lane];

  for (int sm = 0; sm < cnt; ++sm) {
    const int p = base + idxl[wv][sm];
    const float4 q = cxyz4[p];
    const float ox = q.x - kxv, oy = q.y - kyv, oz = q.z - kzv;
    gbuf[wv][lane] = vf[(size_t)p * 64 + lane];
    __threadfence_block();
    float acc = ox * wA0;
    acc = fmaf(oy, wA1, acc);
    acc = fmaf(oz, wA2, acc);
#pragma unroll
    for (int k4 = 0; k4 < 16; ++k4) {
      float4 g4 = *(const float4*)&gbuf[wv][k4 * 4];
      acc = fmaf(g4.x, wB[k4 * 4 + 0], acc);
      acc = fmaf(g4.y, wB[k4 * 4 + 1], acc);
      acc = fmaf(g4.z, wB[k4 * 4 + 2], acc);
      acc = fmaf(g4.w, wB[k4 * 4 + 3], acc);
    }
    hbuf[wv][sm][lane] = fmaxf(fmaf(acc, s0, bb0), 0.f);
    __threadfence_block();
  }
  float mx = -1e30f;
  for (int sm = 0; sm < cnt; ++sm) {
    float acc = 0.f;
#pragma unroll
    for (int k4 = 0; k4 < 16; ++k4) {
      float4 h4 = *(const float4*)&hbuf[wv][sm][k4 * 4];
      acc = fmaf(h4.x, wC[k4 * 4 + 0], acc);
      acc = fmaf(h4.y, wC[k4 * 4 + 1], acc);
      acc = fmaf(h4.z, wC[k4 * 4 + 2], acc);
      acc = fmaf(h4.w, wC[k4 * 4 + 3], acc);
    }
    mx = fmaxf(mx, fmaxf(fmaf(acc, s1, bb1), 0.f));
  }
  feats[outoff + lane] = mx;
}

// ---------------------------------------------------------------------------
// K5: fusion 416 -> 128 + BN + ReLU. one thread per (kp, out-channel).
// ---------------------------------------------------------------------------
__global__ __launch_bounds__(256) void fusion_kernel(
    const float* __restrict__ feats, const float* __restrict__ fw,
    const float* __restrict__ fg, const float* __restrict__ fb,
    float* __restrict__ out) {
  const int gid = blockIdx.x * 256 + threadIdx.x;
  const int kidx = gid >> 7, c = gid & 127;
  const float* f = feats + (size_t)kidx * 416;
  float acc = 0.f;
#pragma unroll 4
  for (int k = 0; k < 416; k += 4) {
    float4 fv = *(const float4*)(f + k);
    acc = fmaf(fv.x, fw[(k + 0) * 128 + c], acc);
    acc = fmaf(fv.y, fw[(k + 1) * 128 + c], acc);
    acc = fmaf(fv.z, fw[(k + 2) * 128 + c], acc);
    acc = fmaf(fv.w, fw[(k + 3) * 128 + c], acc);
  }
  out[gid] = fmaxf(fmaf(acc, fg[c] * kBNS, fb[c]), 0.f);
}

// ---------------------------------------------------------------------------
extern "C" void kernel_launch(void* const* d_in, const int* in_sizes, int n_in,
                              void* d_out, int out_size, void* d_ws, size_t ws_size,
                              hipStream_t stream) {
  (void)in_sizes; (void)n_in; (void)out_size; (void)ws_size;
  const float* pts = (const float*)d_in[0];
  const float* sf  = (const float*)d_in[1];
  const int*   vc  = (const int*)d_in[2];
  const float* vf  = (const float*)d_in[3];
  const float* raw_w0 = (const float*)d_in[4];
  const float* raw_g0 = (const float*)d_in[5];
  const float* raw_b0 = (const float*)d_in[6];
  const float* raw_w1 = (const float*)d_in[7];
  const float* raw_g1 = (const float*)d_in[8];
  const float* raw_b1 = (const float*)d_in[9];
  const float* conv_w0 = (const float*)d_in[10];
  const float* conv_g0 = (const float*)d_in[11];
  const float* conv_b0 = (const float*)d_in[12];
  const float* conv_w1 = (const float*)d_in[13];
  const float* conv_g1 = (const float*)d_in[14];
  const float* conv_b1 = (const float*)d_in[15];
  const float* fus_w = (const float*)d_in[16];
  const float* fus_g = (const float*)d_in[17];
  const float* fus_b = (const float*)d_in[18];
  float* out = (float*)d_out;

  float* W = (float*)d_ws;
  float4* xyz4  = (float4*)W;             // 32768 float4 = 131072 floats
  float4* cxyz4 = (float4*)(W + 131072);  // 16384 float4 = 65536 floats
  float* kx    = W + 196608;              // 4096 each
  float* ky    = W + 200704;
  float* kz    = W + 204800;
  float* feats = W + 208896;              // 4096 * 416
  // fps-only scratch ALIASED into the feats region (fps completes before any
  // feats writes): sorted-pos -> original index permutation
  int* sperm = (int*)(W + 208896);        // 32768 ints

  prep_kernel<<<128, 256, 0, stream>>>(pts, vc, xyz4, cxyz4);
  sort_kernel<<<2, 1024, 0, stream>>>(pts, sperm);
  fps_kernel<<<2, 1024, 0, stream>>>(sperm, xyz4, kx, ky, kz);
  bev_kernel<<<NKPALL, 256, 0, stream>>>(sf, kx, ky, feats);
  raw_sa_kernel<<<2048, 256, 0, stream>>>(xyz4, kx, ky, kz,
                                          raw_w0, raw_g0, raw_b0, raw_w1, raw_g1, raw_b1,
                                          feats);
  conv_sa_kernel<<<2048, 256, 0, stream>>>(cxyz4, vf, kx, ky, kz,
                                           conv_w0, conv_g0, conv_b0, conv_w1, conv_g1, conv_b1,
                                           feats);
  fusion_kernel<<<2048, 256, 0, stream>>>(feats, fus_w, fus_g, fus_b, out);
}